// Round 9
// baseline (180.503 us; speedup 1.0000x reference)
//
#include <hip/hip_runtime.h>
#include <hip/hip_bf16.h>

// Encoder: neigh_feats = mean(raw[idx], axis=1); x = nf @ W; BN(train); LeakyReLU(0.01)
// Inputs: raw[100000,128]f32, W[128,128]f32, gamma[128], beta[128], idx[50000,16]i32
// Output: [50000,128] f32
//
// R12: gather is pinned at 44-48us across THREE layouts and FETCH 94->30->13MB
// (R8's L3-warm replays: fully resident, still 47us). Per-thread 16-load chain
// runs ~4-deep no matter what (regalloc defeated sched_barrier AND inline-asm
// bundles: VGPR 44-48 both times). This round shortens the CHAIN instead:
//   enc_gather_slab4: 4 loads/thread (4 threads per row-half, kg groups),
//   1024-thread blocks (2 blocks/CU -> 2048 thr/CU, ~3x TLP), mean completed
//   by intra-wave shuffle tree, stats via shuffle+LDS + 8-slot atomics (~100K).
// A 4-load chain stays fully in flight even when rolled -> chain latency /4.
// Discriminator: latency-bound -> 15-25us; request-rate-bound -> unchanged
// (then the gather is at a HW divergent-request wall and we're at roofline).
// Slab layout kept (L2-resident, proven). zgemm/bn/numerics unchanged.

#define NTOTAL 100000
#define FEAT   128
#define NB     50000
#define KNEI   16
#define NTILES (NB / 16)      // 3125
#define ZTILES (NTOTAL / 16)  // 6250
#define NSLOT  8
#define NSTRIPE ((NB + 127) / 128)   // 391 (last stripe: 80 rows)

// d_ws layout
#define OFF_PSTAT 0                          // 8*256 f32 = 8 KB
#define OFF_ZC    8192                       // 8 slabs * 100000*16 bf16 = 25.6 MB
#define OFF_XB    (8192 + 25600000)          // 50000*128 bf16 = 12.8 MB
#define WS_NEEDED (OFF_XB + 12800000)

typedef float f32x4 __attribute__((ext_vector_type(4)));
typedef short bf16x8 __attribute__((ext_vector_type(8)));
typedef int   i32x4 __attribute__((ext_vector_type(4)));

__device__ __forceinline__ unsigned short f2bf(float f) {
    union { float f; unsigned u; } v; v.f = f;
    unsigned r = v.u + 0x7FFF + ((v.u >> 16) & 1);   // round-to-nearest-even
    return (unsigned short)(r >> 16);
}

#define WT_LD 136   // bf16 elems; pad 8: 16B-aligned rows
#define A_LD  136
#define SLAB_ELEMS ((size_t)NTOTAL * 16)     // bf16 elems per feature slab

// ---------------- K1: Zc slabs = raw f32 @ W (bf16 MFMA); zero pstats ----------
__global__ __launch_bounds__(256, 4) void enc_zgemm(
    const float* __restrict__ raw, const float* __restrict__ W,
    unsigned short* __restrict__ Zc, float* __restrict__ pstats)
{
    __shared__ unsigned short sWt[128 * WT_LD];  // 34816 B
    __shared__ unsigned short sA[16 * A_LD];     //  4352 B

    const int t = threadIdx.x;

    if (blockIdx.x == 0) {                       // zero stat partials for K2
        #pragma unroll
        for (int i = 0; i < NSLOT; ++i) pstats[t + i * 256] = 0.f;
    }

    // Stage W -> sWt transposed (n-major, k-contig). 64KB coalesced float4 reads.
    #pragma unroll
    for (int i = 0; i < 16; ++i) {
        int e = t + i * 256;                     // float4 index, 4096 total
        float4 w4 = ((const float4*)W)[e];
        int li = e * 4;
        int k = li >> 7, n = li & 127;           // W[k][n..n+3]
        sWt[(n + 0) * WT_LD + k] = f2bf(w4.x);
        sWt[(n + 1) * WT_LD + k] = f2bf(w4.y);
        sWt[(n + 2) * WT_LD + k] = f2bf(w4.z);
        sWt[(n + 3) * WT_LD + k] = f2bf(w4.w);
    }

    const int lane = t & 63;
    const int wv = t >> 6;        // wave 0..3 -> n-chunk of 32
    const int ln = lane & 15;
    const int qd = lane >> 4;     // quad 0..3
    const int c2 = t & 15;        // 16B bf16 chunk within row
    const int g  = t >> 4;        // row 0..15 within tile
    const int n0 = wv * 32 + ln, n1 = n0 + 16;
    const int s0 = wv * 2, s1 = wv * 2 + 1;      // feature slabs for n0, n1

    for (int tile = blockIdx.x; tile < ZTILES; tile += gridDim.x) {
        const int r0 = tile * 16;
        __syncthreads();                         // protect sA reuse
        {
            const float4* rp = (const float4*)&raw[(size_t)(r0 + g) * FEAT + c2 * 8];
            float4 x0 = rp[0], x1 = rp[1];
            uint4 b;
            b.x = (unsigned)f2bf(x0.x) | ((unsigned)f2bf(x0.y) << 16);
            b.y = (unsigned)f2bf(x0.z) | ((unsigned)f2bf(x0.w) << 16);
            b.z = (unsigned)f2bf(x1.x) | ((unsigned)f2bf(x1.y) << 16);
            b.w = (unsigned)f2bf(x1.z) | ((unsigned)f2bf(x1.w) << 16);
            *(uint4*)&sA[g * A_LD + c2 * 8] = b;
        }
        __syncthreads();

        f32x4 acc0 = {0.f, 0.f, 0.f, 0.f}, acc1 = {0.f, 0.f, 0.f, 0.f};
        #pragma unroll
        for (int kt = 0; kt < 4; ++kt) {
            const int k0 = kt * 32 + qd * 8;
            bf16x8 a  = *(const bf16x8*)&sA[ln * A_LD + k0];
            bf16x8 b0 = *(const bf16x8*)&sWt[n0 * WT_LD + k0];
            bf16x8 b1 = *(const bf16x8*)&sWt[n1 * WT_LD + k0];
            acc0 = __builtin_amdgcn_mfma_f32_16x16x32_bf16(a, b0, acc0, 0, 0, 0);
            acc1 = __builtin_amdgcn_mfma_f32_16x16x32_bf16(a, b1, acc1, 0, 0, 0);
        }

        // C/D layout: col=lane&15, row=qd*4+reg. Store into feature slabs.
        #pragma unroll
        for (int ri = 0; ri < 4; ++ri) {
            const int row = r0 + qd * 4 + ri;
            Zc[(size_t)s0 * SLAB_ELEMS + (size_t)row * 16 + ln] = f2bf(acc0[ri]);
            Zc[(size_t)s1 * SLAB_ELEMS + (size_t)row * 16 + ln] = f2bf(acc1[ri]);
        }
    }
}

// ---------------- K2: slab gather+mean, 4 loads/thread; stats partials ---------
// Block b: slab fc=b&7 (XCD-local under round-robin), rows stripe*128..+127.
// 1024 threads. Wave lane = (r_local<<3)|(kg<<1)|h: r_local=lane>>3 (8 rows/wave),
// kg=(lane>>1)&3 (4 neighbor groups of 4), h=lane&1 (16B half of 32B slab row).
__global__ __launch_bounds__(1024, 2) void enc_gather_slab4(
    const unsigned short* __restrict__ Zc, const int* __restrict__ idx,
    unsigned short* __restrict__ xb, float* __restrict__ pstats)
{
    __shared__ int sidx[2048];          // 8 KB: 128 rows x 16 idx
    __shared__ float sRed[2 * 16 * 16]; // 2 KB: s1/s2 per wave x 16 slab-feats

    const int t = threadIdx.x;
    const int fc = blockIdx.x & 7;
    const int stripe = blockIdx.x >> 3;
    const int r0 = stripe * 128;

    {   // stage idx tile (2048 ints), nontemporal, bounds-guarded (last stripe)
        int o0 = r0 * KNEI + t;
        if (o0 < NB * KNEI) sidx[t] = __builtin_nontemporal_load(&idx[o0]);
        int o1 = o0 + 1024;
        if (o1 < NB * KNEI) sidx[t + 1024] = __builtin_nontemporal_load(&idx[o1]);
    }
    __syncthreads();

    const int lane = t & 63;
    const int w  = t >> 6;              // wave 0..15
    const int rl = lane >> 3;           // row within wave 0..7
    const int kg = (lane >> 1) & 3;     // neighbor group 0..3
    const int h  = lane & 1;            // 16B half
    const int r  = w * 8 + rl;          // row within block 0..127
    const int row = r0 + r;
    const bool valid = row < NB;

    const unsigned short* slab = Zc + (size_t)fc * SLAB_ELEMS;

    float a[8];
    #pragma unroll
    for (int j = 0; j < 8; ++j) a[j] = 0.f;

    if (valid) {
        const int* ip = &sidx[r * KNEI + kg * 4];
        uint4 v[4];                     // 4-load chain: stays fully in flight
        #pragma unroll
        for (int kk = 0; kk < 4; ++kk)
            v[kk] = *(const uint4*)&slab[(size_t)ip[kk] * 16 + h * 8];
        __builtin_amdgcn_sched_barrier(0);
        #pragma unroll
        for (int kk = 0; kk < 4; ++kk) {
            a[0] += __uint_as_float(v[kk].x << 16);
            a[1] += __uint_as_float(v[kk].x & 0xFFFF0000u);
            a[2] += __uint_as_float(v[kk].y << 16);
            a[3] += __uint_as_float(v[kk].y & 0xFFFF0000u);
            a[4] += __uint_as_float(v[kk].z << 16);
            a[5] += __uint_as_float(v[kk].z & 0xFFFF0000u);
            a[6] += __uint_as_float(v[kk].w << 16);
            a[7] += __uint_as_float(v[kk].w & 0xFFFF0000u);
        }
    }

    // kg-reduce (strides 4,2 in lane space): kg0 lanes get sum over 16 neighbors.
    #pragma unroll
    for (int j = 0; j < 8; ++j) {
        a[j] += __shfl_down(a[j], 4);
        a[j] += __shfl_down(a[j], 2);
        a[j] *= 0.0625f;
    }

    if (((lane & 6) == 0) && valid) {   // kg==0 lanes: x row-half complete
        uint4 b;
        b.x = (unsigned)f2bf(a[0]) | ((unsigned)f2bf(a[1]) << 16);
        b.y = (unsigned)f2bf(a[2]) | ((unsigned)f2bf(a[3]) << 16);
        b.z = (unsigned)f2bf(a[4]) | ((unsigned)f2bf(a[5]) << 16);
        b.w = (unsigned)f2bf(a[6]) | ((unsigned)f2bf(a[7]) << 16);
        *(uint4*)&xb[(size_t)row * FEAT + fc * 16 + h * 8] = b;
    }

    // Row-reduce for stats (strides 32,16,8 preserve kg/h bits): lanes 0,1 end
    // with sums over the wave's 8 rows for halves h=0,1. Invalid rows are 0.
    float q[8];
    #pragma unroll
    for (int j = 0; j < 8; ++j) q[j] = a[j] * a[j];
    #pragma unroll
    for (int j = 0; j < 8; ++j) {
        a[j] += __shfl_down(a[j], 32); q[j] += __shfl_down(q[j], 32);
        a[j] += __shfl_down(a[j], 16); q[j] += __shfl_down(q[j], 16);
        a[j] += __shfl_down(a[j], 8);  q[j] += __shfl_down(q[j], 8);
    }
    if (lane < 2) {
        #pragma unroll
        for (int j = 0; j < 8; ++j) {
            sRed[w * 16 + h * 8 + j]       = a[j];
            sRed[256 + w * 16 + h * 8 + j] = q[j];
        }
    }
    __syncthreads();
    if (t < 16) {
        float u1 = 0.f, u2 = 0.f;
        #pragma unroll
        for (int ww = 0; ww < 16; ++ww) {
            u1 += sRed[ww * 16 + t];
            u2 += sRed[256 + ww * 16 + t];
        }
        const int slot = stripe & (NSLOT - 1);
        atomicAdd(&pstats[slot * 256 + fc * 16 + t], u1);
        atomicAdd(&pstats[slot * 256 + 128 + fc * 16 + t], u2);
    }
}

// ---------------- K3: reduce slots -> scale/shift; xb -> out -------------------
__global__ __launch_bounds__(256) void enc_bn(
    const unsigned short* __restrict__ xb, float* __restrict__ out,
    const float* __restrict__ pstats,
    const float* __restrict__ gamma, const float* __restrict__ beta)
{
    __shared__ float sScale[FEAT], sShift[FEAT];
    const int t = threadIdx.x;
    if (t < FEAT) {
        float s1 = 0.f, s2 = 0.f;
        #pragma unroll
        for (int sl = 0; sl < NSLOT; ++sl) {
            s1 += pstats[sl * 256 + t];
            s2 += pstats[sl * 256 + 128 + t];
        }
        float mean = s1 * (1.0f / NB);
        float var = s2 * (1.0f / NB) - mean * mean;
        float sc = gamma[t] * rsqrtf(var + 1e-5f);
        sScale[t] = sc;
        sShift[t] = beta[t] - mean * sc;
    }
    __syncthreads();

    const int f8 = (t & 15) * 8;
    const float4 sc0 = *(const float4*)&sScale[f8], sc1 = *(const float4*)&sScale[f8 + 4];
    const float4 sh0 = *(const float4*)&sShift[f8], sh1 = *(const float4*)&sShift[f8 + 4];

    const uint4* x4 = (const uint4*)xb;
    float4* o4 = (float4*)out;
    const int total8 = NB * FEAT / 8;          // 800k
    for (int e = blockIdx.x * 256 + t; e < total8; e += gridDim.x * 256) {
        uint4 v = x4[e];
        float4 r0, r1; float y;
        y = __uint_as_float(v.x << 16)        * sc0.x + sh0.x; r0.x = (y >= 0.f) ? y : 0.01f * y;
        y = __uint_as_float(v.x & 0xFFFF0000u)* sc0.y + sh0.y; r0.y = (y >= 0.f) ? y : 0.01f * y;
        y = __uint_as_float(v.y << 16)        * sc0.z + sh0.z; r0.z = (y >= 0.f) ? y : 0.01f * y;
        y = __uint_as_float(v.y & 0xFFFF0000u)* sc0.w + sh0.w; r0.w = (y >= 0.f) ? y : 0.01f * y;
        y = __uint_as_float(v.z << 16)        * sc1.x + sh1.x; r1.x = (y >= 0.f) ? y : 0.01f * y;
        y = __uint_as_float(v.z & 0xFFFF0000u)* sc1.y + sh1.y; r1.y = (y >= 0.f) ? y : 0.01f * y;
        y = __uint_as_float(v.w << 16)        * sc1.z + sh1.z; r1.z = (y >= 0.f) ? y : 0.01f * y;
        y = __uint_as_float(v.w & 0xFFFF0000u)* sc1.w + sh1.w; r1.w = (y >= 0.f) ? y : 0.01f * y;
        o4[e * 2] = r0; o4[e * 2 + 1] = r1;
    }
}

// ======================= fallback (f32 path, tiny ws) ==========================
__global__ __launch_bounds__(256, 4) void enc_gemm_f(
    const float* __restrict__ raw, const float* __restrict__ W,
    const int* __restrict__ idx, float* __restrict__ out,
    float* __restrict__ gstats)
{
    __shared__ unsigned short sWt[128 * WT_LD];
    __shared__ unsigned short sA[16 * A_LD];
    __shared__ int sidx[256];
    const int t = threadIdx.x;
    #pragma unroll 4
    for (int i = 0; i < 64; ++i) {
        int e = t + i * 256;
        int f = e >> 7, n = e & 127;
        sWt[n * WT_LD + f] = f2bf(W[e]);
    }
    const int lane = t & 63, wv = t >> 6, ln = lane & 15, qd = lane >> 4;
    const int c = t & 31, g = t >> 5;
    const int n0 = wv * 32 + ln, n1 = n0 + 16;
    float s1a = 0.f, s2a = 0.f, s1b = 0.f, s2b = 0.f;
    const float4* raw4 = (const float4*)raw;
    for (int tile = blockIdx.x; tile < NTILES; tile += gridDim.x) {
        const int i0 = tile * 16;
        __syncthreads();
        sidx[t] = idx[i0 * KNEI + t];
        __syncthreads();
        #pragma unroll
        for (int rr = 0; rr < 2; ++rr) {
            const int r = g * 2 + rr;
            const int* ip = &sidx[r * KNEI];
            float4 acc = {0.f, 0.f, 0.f, 0.f};
            #pragma unroll
            for (int k = 0; k < KNEI; ++k) {
                float4 v = raw4[(size_t)ip[k] * 32 + c];
                acc.x += v.x; acc.y += v.y; acc.z += v.z; acc.w += v.w;
            }
            ushort4 b;
            b.x = f2bf(acc.x * 0.0625f); b.y = f2bf(acc.y * 0.0625f);
            b.z = f2bf(acc.z * 0.0625f); b.w = f2bf(acc.w * 0.0625f);
            *(ushort4*)&sA[r * A_LD + c * 4] = b;
        }
        __syncthreads();
        f32x4 acc0 = {0.f, 0.f, 0.f, 0.f}, acc1 = {0.f, 0.f, 0.f, 0.f};
        #pragma unroll
        for (int kt = 0; kt < 4; ++kt) {
            const int k0 = kt * 32 + qd * 8;
            bf16x8 a  = *(const bf16x8*)&sA[ln * A_LD + k0];
            bf16x8 b0 = *(const bf16x8*)&sWt[n0 * WT_LD + k0];
            bf16x8 b1 = *(const bf16x8*)&sWt[n1 * WT_LD + k0];
            acc0 = __builtin_amdgcn_mfma_f32_16x16x32_bf16(a, b0, acc0, 0, 0, 0);
            acc1 = __builtin_amdgcn_mfma_f32_16x16x32_bf16(a, b1, acc1, 0, 0, 0);
        }
        #pragma unroll
        for (int ri = 0; ri < 4; ++ri) {
            const int row = i0 + qd * 4 + ri;
            float v0 = acc0[ri], v1 = acc1[ri];
            out[row * FEAT + n0] = v0;
            out[row * FEAT + n1] = v1;
            s1a += v0; s2a += v0 * v0;
            s1b += v1; s2b += v1 * v1;
        }
    }
    s1a += __shfl_down(s1a, 32); s1a += __shfl_down(s1a, 16);
    s2a += __shfl_down(s2a, 32); s2a += __shfl_down(s2a, 16);
    s1b += __shfl_down(s1b, 32); s1b += __shfl_down(s1b, 16);
    s2b += __shfl_down(s2b, 32); s2b += __shfl_down(s2b, 16);
    if (qd == 0) {
        atomicAdd(&gstats[n0], s1a);
        atomicAdd(&gstats[FEAT + n0], s2a);
        atomicAdd(&gstats[n1], s1b);
        atomicAdd(&gstats[FEAT + n1], s2b);
    }
}

__global__ __launch_bounds__(256) void enc_bn_f(
    float* __restrict__ out, const float* __restrict__ gstats,
    const float* __restrict__ gamma, const float* __restrict__ beta)
{
    __shared__ float sScale[FEAT], sShift[FEAT];
    const int t = threadIdx.x;
    if (t < FEAT) {
        float s1 = gstats[t], s2 = gstats[FEAT + t];
        float mean = s1 * (1.0f / NB);
        float var = s2 * (1.0f / NB) - mean * mean;
        float sc = gamma[t] * rsqrtf(var + 1e-5f);
        sScale[t] = sc;
        sShift[t] = beta[t] - mean * sc;
    }
    __syncthreads();
    const int f4 = (t & 31) * 4;
    const float4 sc = *(const float4*)&sScale[f4];
    const float4 sh = *(const float4*)&sShift[f4];
    const int total4 = NB * FEAT / 4;
    float4* o4 = (float4*)out;
    for (int e = blockIdx.x * 256 + t; e < total4; e += gridDim.x * 256) {
        float4 v = o4[e];
        float4 r; float y;
        y = v.x * sc.x + sh.x; r.x = (y >= 0.f) ? y : 0.01f * y;
        y = v.y * sc.y + sh.y; r.y = (y >= 0.f) ? y : 0.01f * y;
        y = v.z * sc.z + sh.z; r.z = (y >= 0.f) ? y : 0.01f * y;
        y = v.w * sc.w + sh.w; r.w = (y >= 0.f) ? y : 0.01f * y;
        o4[e] = r;
    }
}

extern "C" void kernel_launch(void* const* d_in, const int* in_sizes, int n_in,
                              void* d_out, int out_size, void* d_ws, size_t ws_size,
                              hipStream_t stream) {
    const float* raw   = (const float*)d_in[0];
    const float* W     = (const float*)d_in[1];
    const float* gamma = (const float*)d_in[2];
    const float* beta  = (const float*)d_in[3];
    const int*   idx   = (const int*)d_in[4];
    float* out = (float*)d_out;

    char* ws = (char*)d_ws;

    if (ws_size >= WS_NEEDED) {
        float* pstats      = (float*)(ws + OFF_PSTAT);
        unsigned short* Zc = (unsigned short*)(ws + OFF_ZC);
        unsigned short* xb = (unsigned short*)(ws + OFF_XB);
        enc_zgemm<<<1042, 256, 0, stream>>>(raw, W, Zc, pstats);
        enc_gather_slab4<<<NSTRIPE * 8, 1024, 0, stream>>>(Zc, idx, xb, pstats);
        enc_bn<<<1024, 256, 0, stream>>>(xb, out, pstats, gamma, beta);
    } else {
        float* gstats = (float*)(ws + OFF_PSTAT);
        (void)hipMemsetAsync(gstats, 0, 2 * FEAT * sizeof(float), stream);
        enc_gemm_f<<<1024, 256, 0, stream>>>(raw, W, idx, out, gstats);
        enc_bn_f<<<1024, 256, 0, stream>>>(out, gstats, gamma, beta);
    }
}

// Round 10
// 146.792 us; speedup vs baseline: 1.2297x; 1.2297x over previous
//
#include <hip/hip_runtime.h>
#include <hip/hip_bf16.h>

// Encoder: neigh_feats = mean(raw[idx], axis=1); x = nf @ W; BN(train); LeakyReLU(0.01)
// Inputs: raw[100000,128]f32, W[128,128]f32, gamma[128], beta[128], idx[50000,16]i32
// Output: [50000,128] f32
//
// R13 (final): revert to the session-best R2 configuration (measured 145.26us).
// Experiment matrix R0-R9 established:
//  - gather floor ~44us = HW divergent-request wall (0.45 16B-req/cy/CU):
//    invariant across row-major/slab layouts, L2/L3 residency (FETCH 94->30->13MB),
//    MLP forcing (sched_barrier, inline-asm bundles), chain 16->4, TLP x3.
//  - grid-wide sync pathological on this stack (coop x2 + manual barrier:
//    ~650 GB/s, idle pipes) -> 3 normal dispatches is optimal structure.
//  - conv (13us) and bn (6us) are at streaming-BW roofline.
// Structure: conv (raw->bf16 + Wt + zero stats) -> fused gather+MFMA+stats -> bn.

#define NTOTAL 100000
#define FEAT   128
#define NB     50000
#define KNEI   16
#define NTILES (NB / 16)   // 3125 exact

// d_ws layout (bf16 path)
#define OFF_STATS 0                         // 256 f32 = 1 KB
#define OFF_WT    1024                      // 128*128 bf16 = 32 KB
#define OFF_RAWB  33792                     // 100000*128 bf16 = 25.6 MB
#define OFF_XB    (33792 + 25600000)        // 50000*128 bf16 = 12.8 MB
#define WS_NEEDED (OFF_XB + 12800000)

typedef float f32x4 __attribute__((ext_vector_type(4)));
typedef short bf16x8 __attribute__((ext_vector_type(8)));

__device__ __forceinline__ unsigned short f2bf(float f) {
    union { float f; unsigned u; } v; v.f = f;
    unsigned r = v.u + 0x7FFF + ((v.u >> 16) & 1);   // round-to-nearest-even
    return (unsigned short)(r >> 16);
}

#define WT_LD 136   // bf16 elems; pad 8: 16B-aligned rows, 2-way banks only (free)
#define A_LD  136

// ---------------- conv: raw f32 -> bf16, W -> Wt bf16 transposed, zero stats ----
__global__ __launch_bounds__(256) void enc_conv(
    const float* __restrict__ raw, const float* __restrict__ W,
    unsigned short* __restrict__ rawb, unsigned short* __restrict__ Wt,
    float* __restrict__ gstats)
{
    const int t = threadIdx.x;
    if (blockIdx.x < 64) {               // Wt[n*128+k] = bf16(W[k*128+n]), coalesced writes
        int e = blockIdx.x * 256 + t;    // 0..16383
        int n = e >> 7, k = e & 127;
        Wt[e] = f2bf(W[k * FEAT + n]);
    }
    if (blockIdx.x == 64 && t < 2 * FEAT) gstats[t] = 0.f;

    const float4* raw4 = (const float4*)raw;
    ushort4* rb4 = (ushort4*)rawb;
    const int NQ = NTOTAL * FEAT / 4;    // 3.2M
    for (int e = blockIdx.x * 256 + t; e < NQ; e += gridDim.x * 256) {
        float4 v = raw4[e];
        ushort4 b;
        b.x = f2bf(v.x); b.y = f2bf(v.y); b.z = f2bf(v.z); b.w = f2bf(v.w);
        rb4[e] = b;
    }
}

// ---------------- gemm (bf16 path): gather bf16 rows, MFMA, x->bf16, stats -------
__global__ __launch_bounds__(256, 4) void enc_gemm_b(
    const unsigned short* __restrict__ rawb, const unsigned short* __restrict__ Wt,
    const int* __restrict__ idx, unsigned short* __restrict__ xb,
    float* __restrict__ gstats)
{
    __shared__ unsigned short sWt[128 * WT_LD];  // 34816 B
    __shared__ unsigned short sA[16 * A_LD];     //  4352 B
    __shared__ int sidx[256];                    //  1024 B

    const int t = threadIdx.x;

    // Stage Wt (already bf16, n-major) into padded LDS: 2048 16B chunks, coalesced.
    #pragma unroll
    for (int i = 0; i < 8; ++i) {
        int e = t + i * 256;
        int n = e >> 4, c = e & 15;
        *(uint4*)&sWt[n * WT_LD + c * 8] = *(const uint4*)&Wt[n * 128 + c * 8];
    }

    const int lane = t & 63;
    const int wv = t >> 6;        // wave 0..3 -> n-chunk of 32
    const int ln = lane & 15;
    const int qd = lane >> 4;     // quad 0..3
    const int c2 = t & 15;        // 16B chunk within 256B bf16 row
    const int g  = t >> 4;        // output row 0..15
    const int n0 = wv * 32 + ln, n1 = n0 + 16;

    float s1a = 0.f, s2a = 0.f, s1b = 0.f, s2b = 0.f;

    for (int tile = blockIdx.x; tile < NTILES; tile += gridDim.x) {
        const int i0 = tile * 16;
        __syncthreads();                       // protect sidx/sA reuse (fences sWt on iter 0)
        sidx[t] = idx[i0 * KNEI + t];          // 256 ints, coalesced
        __syncthreads();

        // Gather + mean: thread owns output row g, 16B chunk c2. The 16-load
        // cluster + sched_barrier gives ~8 in flight (best regalloc will allow;
        // gather is at the HW divergent-request wall regardless -- see header).
        {
            const int* ip = &sidx[g * KNEI];
            uint4 v[16];
            #pragma unroll
            for (int k = 0; k < KNEI; ++k)
                v[k] = *(const uint4*)&rawb[(size_t)ip[k] * FEAT + c2 * 8];
            __builtin_amdgcn_sched_barrier(0);
            float a0=0.f,a1=0.f,a2=0.f,a3=0.f,a4=0.f,a5=0.f,a6=0.f,a7=0.f;
            #pragma unroll
            for (int k = 0; k < KNEI; ++k) {
                a0 += __uint_as_float(v[k].x << 16);
                a1 += __uint_as_float(v[k].x & 0xFFFF0000u);
                a2 += __uint_as_float(v[k].y << 16);
                a3 += __uint_as_float(v[k].y & 0xFFFF0000u);
                a4 += __uint_as_float(v[k].z << 16);
                a5 += __uint_as_float(v[k].z & 0xFFFF0000u);
                a6 += __uint_as_float(v[k].w << 16);
                a7 += __uint_as_float(v[k].w & 0xFFFF0000u);
            }
            uint4 b;
            b.x = (unsigned)f2bf(a0 * 0.0625f) | ((unsigned)f2bf(a1 * 0.0625f) << 16);
            b.y = (unsigned)f2bf(a2 * 0.0625f) | ((unsigned)f2bf(a3 * 0.0625f) << 16);
            b.z = (unsigned)f2bf(a4 * 0.0625f) | ((unsigned)f2bf(a5 * 0.0625f) << 16);
            b.w = (unsigned)f2bf(a6 * 0.0625f) | ((unsigned)f2bf(a7 * 0.0625f) << 16);
            *(uint4*)&sA[g * A_LD + c2 * 8] = b;
        }
        __syncthreads();

        // MFMA: wave wv computes n-tiles n0, n1 for all 16 rows.
        f32x4 acc0 = {0.f, 0.f, 0.f, 0.f}, acc1 = {0.f, 0.f, 0.f, 0.f};
        #pragma unroll
        for (int kt = 0; kt < 4; ++kt) {
            const int k0 = kt * 32 + qd * 8;
            bf16x8 a  = *(const bf16x8*)&sA[ln * A_LD + k0];
            bf16x8 b0 = *(const bf16x8*)&sWt[n0 * WT_LD + k0];
            bf16x8 b1 = *(const bf16x8*)&sWt[n1 * WT_LD + k0];
            acc0 = __builtin_amdgcn_mfma_f32_16x16x32_bf16(a, b0, acc0, 0, 0, 0);
            acc1 = __builtin_amdgcn_mfma_f32_16x16x32_bf16(a, b1, acc1, 0, 0, 0);
        }

        // Epilogue: C/D layout col=lane&15, row=qd*4+reg. x -> bf16 ws; stats in f32.
        #pragma unroll
        for (int ri = 0; ri < 4; ++ri) {
            const int row = i0 + qd * 4 + ri;
            float v0 = acc0[ri], v1 = acc1[ri];
            xb[row * FEAT + n0] = f2bf(v0);
            xb[row * FEAT + n1] = f2bf(v1);
            s1a += v0; s2a += v0 * v0;
            s1b += v1; s2b += v1 * v1;
        }
    }

    s1a += __shfl_down(s1a, 32); s1a += __shfl_down(s1a, 16);
    s2a += __shfl_down(s2a, 32); s2a += __shfl_down(s2a, 16);
    s1b += __shfl_down(s1b, 32); s1b += __shfl_down(s1b, 16);
    s2b += __shfl_down(s2b, 32); s2b += __shfl_down(s2b, 16);
    if (qd == 0) {
        atomicAdd(&gstats[n0], s1a);
        atomicAdd(&gstats[FEAT + n0], s2a);
        atomicAdd(&gstats[n1], s1b);
        atomicAdd(&gstats[FEAT + n1], s2b);
    }
}

// ---------------- bn (bf16 path): xb -> normalized f32 out ----------------------
__global__ __launch_bounds__(256) void enc_bn_b(
    const unsigned short* __restrict__ xb, float* __restrict__ out,
    const float* __restrict__ gstats,
    const float* __restrict__ gamma, const float* __restrict__ beta)
{
    __shared__ float sScale[FEAT], sShift[FEAT];
    const int t = threadIdx.x;
    if (t < FEAT) {
        float s1 = gstats[t], s2 = gstats[FEAT + t];
        float mean = s1 * (1.0f / NB);
        float var = s2 * (1.0f / NB) - mean * mean;
        float sc = gamma[t] * rsqrtf(var + 1e-5f);
        sScale[t] = sc;
        sShift[t] = beta[t] - mean * sc;
    }
    __syncthreads();

    const int f8 = (t & 15) * 8;               // thread-invariant feature octet
    const float4 sc0 = *(const float4*)&sScale[f8], sc1 = *(const float4*)&sScale[f8 + 4];
    const float4 sh0 = *(const float4*)&sShift[f8], sh1 = *(const float4*)&sShift[f8 + 4];

    const uint4* x4 = (const uint4*)xb;
    float4* o4 = (float4*)out;
    const int total8 = NB * FEAT / 8;          // 800k
    for (int e = blockIdx.x * 256 + t; e < total8; e += gridDim.x * 256) {
        uint4 v = x4[e];
        float4 r0, r1; float y;
        y = __uint_as_float(v.x << 16)        * sc0.x + sh0.x; r0.x = (y >= 0.f) ? y : 0.01f * y;
        y = __uint_as_float(v.x & 0xFFFF0000u)* sc0.y + sh0.y; r0.y = (y >= 0.f) ? y : 0.01f * y;
        y = __uint_as_float(v.y << 16)        * sc0.z + sh0.z; r0.z = (y >= 0.f) ? y : 0.01f * y;
        y = __uint_as_float(v.y & 0xFFFF0000u)* sc0.w + sh0.w; r0.w = (y >= 0.f) ? y : 0.01f * y;
        y = __uint_as_float(v.z << 16)        * sc1.x + sh1.x; r1.x = (y >= 0.f) ? y : 0.01f * y;
        y = __uint_as_float(v.z & 0xFFFF0000u)* sc1.y + sh1.y; r1.y = (y >= 0.f) ? y : 0.01f * y;
        y = __uint_as_float(v.w << 16)        * sc1.z + sh1.z; r1.z = (y >= 0.f) ? y : 0.01f * y;
        y = __uint_as_float(v.w & 0xFFFF0000u)* sc1.w + sh1.w; r1.w = (y >= 0.f) ? y : 0.01f * y;
        o4[e * 2] = r0; o4[e * 2 + 1] = r1;
    }
}

// ======================= fallback (f32 path, tiny ws) ==========================
__global__ __launch_bounds__(256, 4) void enc_gemm_f(
    const float* __restrict__ raw, const float* __restrict__ W,
    const int* __restrict__ idx, float* __restrict__ out,
    float* __restrict__ gstats)
{
    __shared__ unsigned short sWt[128 * WT_LD];
    __shared__ unsigned short sA[16 * A_LD];
    __shared__ int sidx[256];
    const int t = threadIdx.x;
    #pragma unroll 4
    for (int i = 0; i < 64; ++i) {
        int e = t + i * 256;
        int f = e >> 7, n = e & 127;
        sWt[n * WT_LD + f] = f2bf(W[e]);
    }
    const int lane = t & 63, wv = t >> 6, ln = lane & 15, qd = lane >> 4;
    const int c = t & 31, g = t >> 5;
    const int n0 = wv * 32 + ln, n1 = n0 + 16;
    float s1a = 0.f, s2a = 0.f, s1b = 0.f, s2b = 0.f;
    const float4* raw4 = (const float4*)raw;
    for (int tile = blockIdx.x; tile < NTILES; tile += gridDim.x) {
        const int i0 = tile * 16;
        __syncthreads();
        sidx[t] = idx[i0 * KNEI + t];
        __syncthreads();
        #pragma unroll
        for (int rr = 0; rr < 2; ++rr) {
            const int r = g * 2 + rr;
            const int* ip = &sidx[r * KNEI];
            float4 acc = {0.f, 0.f, 0.f, 0.f};
            #pragma unroll
            for (int k = 0; k < KNEI; ++k) {
                float4 v = raw4[(size_t)ip[k] * 32 + c];
                acc.x += v.x; acc.y += v.y; acc.z += v.z; acc.w += v.w;
            }
            ushort4 b;
            b.x = f2bf(acc.x * 0.0625f); b.y = f2bf(acc.y * 0.0625f);
            b.z = f2bf(acc.z * 0.0625f); b.w = f2bf(acc.w * 0.0625f);
            *(ushort4*)&sA[r * A_LD + c * 4] = b;
        }
        __syncthreads();
        f32x4 acc0 = {0.f, 0.f, 0.f, 0.f}, acc1 = {0.f, 0.f, 0.f, 0.f};
        #pragma unroll
        for (int kt = 0; kt < 4; ++kt) {
            const int k0 = kt * 32 + qd * 8;
            bf16x8 a  = *(const bf16x8*)&sA[ln * A_LD + k0];
            bf16x8 b0 = *(const bf16x8*)&sWt[n0 * WT_LD + k0];
            bf16x8 b1 = *(const bf16x8*)&sWt[n1 * WT_LD + k0];
            acc0 = __builtin_amdgcn_mfma_f32_16x16x32_bf16(a, b0, acc0, 0, 0, 0);
            acc1 = __builtin_amdgcn_mfma_f32_16x16x32_bf16(a, b1, acc1, 0, 0, 0);
        }
        #pragma unroll
        for (int ri = 0; ri < 4; ++ri) {
            const int row = i0 + qd * 4 + ri;
            float v0 = acc0[ri], v1 = acc1[ri];
            out[row * FEAT + n0] = v0;
            out[row * FEAT + n1] = v1;
            s1a += v0; s2a += v0 * v0;
            s1b += v1; s2b += v1 * v1;
        }
    }
    s1a += __shfl_down(s1a, 32); s1a += __shfl_down(s1a, 16);
    s2a += __shfl_down(s2a, 32); s2a += __shfl_down(s2a, 16);
    s1b += __shfl_down(s1b, 32); s1b += __shfl_down(s1b, 16);
    s2b += __shfl_down(s2b, 32); s2b += __shfl_down(s2b, 16);
    if (qd == 0) {
        atomicAdd(&gstats[n0], s1a);
        atomicAdd(&gstats[FEAT + n0], s2a);
        atomicAdd(&gstats[n1], s1b);
        atomicAdd(&gstats[FEAT + n1], s2b);
    }
}

__global__ __launch_bounds__(256) void enc_bn_f(
    float* __restrict__ out, const float* __restrict__ gstats,
    const float* __restrict__ gamma, const float* __restrict__ beta)
{
    __shared__ float sScale[FEAT], sShift[FEAT];
    const int t = threadIdx.x;
    if (t < FEAT) {
        float s1 = gstats[t], s2 = gstats[FEAT + t];
        float mean = s1 * (1.0f / NB);
        float var = s2 * (1.0f / NB) - mean * mean;
        float sc = gamma[t] * rsqrtf(var + 1e-5f);
        sScale[t] = sc;
        sShift[t] = beta[t] - mean * sc;
    }
    __syncthreads();
    const int f4 = (t & 31) * 4;
    const float4 sc = *(const float4*)&sScale[f4];
    const float4 sh = *(const float4*)&sShift[f4];
    const int total4 = NB * FEAT / 4;
    float4* o4 = (float4*)out;
    for (int e = blockIdx.x * 256 + t; e < total4; e += gridDim.x * 256) {
        float4 v = o4[e];
        float4 r; float y;
        y = v.x * sc.x + sh.x; r.x = (y >= 0.f) ? y : 0.01f * y;
        y = v.y * sc.y + sh.y; r.y = (y >= 0.f) ? y : 0.01f * y;
        y = v.z * sc.z + sh.z; r.z = (y >= 0.f) ? y : 0.01f * y;
        y = v.w * sc.w + sh.w; r.w = (y >= 0.f) ? y : 0.01f * y;
        o4[e] = r;
    }
}

extern "C" void kernel_launch(void* const* d_in, const int* in_sizes, int n_in,
                              void* d_out, int out_size, void* d_ws, size_t ws_size,
                              hipStream_t stream) {
    const float* raw   = (const float*)d_in[0];
    const float* W     = (const float*)d_in[1];
    const float* gamma = (const float*)d_in[2];
    const float* beta  = (const float*)d_in[3];
    const int*   idx   = (const int*)d_in[4];
    float* out = (float*)d_out;

    char* ws = (char*)d_ws;
    float* gstats = (float*)(ws + OFF_STATS);

    if (ws_size >= WS_NEEDED) {
        unsigned short* Wt   = (unsigned short*)(ws + OFF_WT);
        unsigned short* rawb = (unsigned short*)(ws + OFF_RAWB);
        unsigned short* xb   = (unsigned short*)(ws + OFF_XB);
        enc_conv<<<2048, 256, 0, stream>>>(raw, W, rawb, Wt, gstats);
        enc_gemm_b<<<1024, 256, 0, stream>>>(rawb, Wt, idx, xb, gstats);
        enc_bn_b<<<1024, 256, 0, stream>>>(xb, out, gstats, gamma, beta);
    } else {
        hipMemsetAsync(gstats, 0, 2 * FEAT * sizeof(float), stream);
        enc_gemm_f<<<1024, 256, 0, stream>>>(raw, W, idx, out, gstats);
        enc_bn_f<<<1024, 256, 0, stream>>>(out, gstats, gamma, beta);
    }
}